// Round 1
// baseline (15315.918 us; speedup 1.0000x reference)
//
#include <hip/hip_runtime.h>
#include <math.h>

#define TOK     2048
#define DM      1024
#define SLEN    1024
#define NHEAD   16
#define HDIM    64
#define DFFN    4096
#define RHID    128
#define NLAY    12
#define NVOCAB  32000
#define LNEPS   1e-5f

// ---------------- GEMM: C[M,N] = act(A[M,K]@B[K,N] + bias (+ Rsd)) ----------------
// BM=128, BN=64, BK=16, 256 threads, 8x4 micro-tile per thread.
template<int RELU, int RES>
__global__ __launch_bounds__(256)
void gemm_k(const float* __restrict__ A, const float* __restrict__ B,
            const float* __restrict__ bias, const float* __restrict__ Rsd,
            float* __restrict__ C, int M, int N, int K)
{
    constexpr int BM = 128, BN = 64, BK = 16;
    __shared__ float As[BK][BM];      // A transposed: As[k][m]
    __shared__ float Bs[BK][BN + 4];  // padded to dodge bank conflicts
    const int tid = threadIdx.x;
    const int m0 = blockIdx.x * BM;
    const int n0 = blockIdx.y * BN;
    const int mi = tid >> 4;           // 0..15 -> rows mi*8..+7
    const int ni = tid & 15;           // 0..15 -> cols ni*4..+3
    const int ar = tid >> 1;           // 0..127 A row within tile
    const int ac = (tid & 1) * 8;      // col offset 0 or 8
    const int br = tid >> 4;           // 0..15 B row within tile
    const int bc = (tid & 15) * 4;     // B col (float4)
    const float* Arow = A + (size_t)(m0 + ar) * K + ac;

    float acc[8][4];
#pragma unroll
    for (int i = 0; i < 8; i++)
#pragma unroll
        for (int j = 0; j < 4; j++) acc[i][j] = 0.f;

    for (int k0 = 0; k0 < K; k0 += BK) {
        float4 a0 = *(const float4*)(Arow + k0);
        float4 a1 = *(const float4*)(Arow + k0 + 4);
        float4 b0 = *(const float4*)(B + (size_t)(k0 + br) * N + n0 + bc);
        __syncthreads();
        As[ac + 0][ar] = a0.x; As[ac + 1][ar] = a0.y;
        As[ac + 2][ar] = a0.z; As[ac + 3][ar] = a0.w;
        As[ac + 4][ar] = a1.x; As[ac + 5][ar] = a1.y;
        As[ac + 6][ar] = a1.z; As[ac + 7][ar] = a1.w;
        *(float4*)&Bs[br][bc] = b0;
        __syncthreads();
#pragma unroll
        for (int kk = 0; kk < BK; kk++) {
            float a[8], b[4];
            *(float4*)&a[0] = *(const float4*)&As[kk][mi * 8];
            *(float4*)&a[4] = *(const float4*)&As[kk][mi * 8 + 4];
            *(float4*)&b[0] = *(const float4*)&Bs[kk][ni * 4];
#pragma unroll
            for (int i = 0; i < 8; i++)
#pragma unroll
                for (int j = 0; j < 4; j++)
                    acc[i][j] = fmaf(a[i], b[j], acc[i][j]);
        }
    }
    const int nn = n0 + ni * 4;
    float4 bi = *(const float4*)&bias[nn];
#pragma unroll
    for (int i = 0; i < 8; i++) {
        const size_t m = (size_t)(m0 + mi * 8 + i);
        float4 v;
        v.x = acc[i][0] + bi.x; v.y = acc[i][1] + bi.y;
        v.z = acc[i][2] + bi.z; v.w = acc[i][3] + bi.w;
        if (RES) {
            float4 r = *(const float4*)(Rsd + m * N + nn);
            v.x += r.x; v.y += r.y; v.z += r.z; v.w += r.w;
        }
        if (RELU) {
            v.x = fmaxf(v.x, 0.f); v.y = fmaxf(v.y, 0.f);
            v.z = fmaxf(v.z, 0.f); v.w = fmaxf(v.w, 0.f);
        }
        *(float4*)(C + m * N + nn) = v;
    }
}

// ---------------- Embedding + positional encoding ----------------
__global__ __launch_bounds__(256)
void emb_k(const int* __restrict__ x, const float* __restrict__ emb,
           float* __restrict__ h)
{
    const int t = blockIdx.x;             // token 0..2047
    const int s = t & (SLEN - 1);         // position
    const int d0 = threadIdx.x * 4;
    const int tokid = x[t];
    float4 e = *(const float4*)(emb + (size_t)tokid * DM + d0);
    const float po = (float)s;
    const float fac = -9.210340371976184f / 1024.f;  // -ln(10000)/D
    float pe[4];
#pragma unroll
    for (int u = 0; u < 4; u++) {
        int d = d0 + u;
        float freq = expf(fac * (float)(d & ~1));
        pe[u] = (d & 1) ? cosf(po * freq) : sinf(po * freq);
    }
    float4 r;
    r.x = e.x * 32.f + pe[0]; r.y = e.y * 32.f + pe[1];
    r.z = e.z * 32.f + pe[2]; r.w = e.w * 32.f + pe[3];
    *(float4*)(h + (size_t)t * DM + d0) = r;
}

// ---------------- LayerNorm (in place, one block per row) ----------------
__global__ __launch_bounds__(256)
void ln_k(float* __restrict__ H, const float* __restrict__ g,
          const float* __restrict__ b)
{
    const int row = blockIdx.x, tid = threadIdx.x;
    float* p = H + (size_t)row * DM + tid * 4;
    float4 v = *(float4*)p;
    __shared__ float red[4];
    __shared__ float mean_s, inv_s;

    float s = v.x + v.y + v.z + v.w;
#pragma unroll
    for (int off = 32; off; off >>= 1) s += __shfl_down(s, off);
    if ((tid & 63) == 0) red[tid >> 6] = s;
    __syncthreads();
    if (tid == 0) mean_s = (red[0] + red[1] + red[2] + red[3]) * (1.f / DM);
    __syncthreads();
    const float mu = mean_s;
    float dx = v.x - mu, dy = v.y - mu, dz = v.z - mu, dw = v.w - mu;
    float q = dx * dx + dy * dy + dz * dz + dw * dw;
#pragma unroll
    for (int off = 32; off; off >>= 1) q += __shfl_down(q, off);
    if ((tid & 63) == 0) red[tid >> 6] = q;
    __syncthreads();
    if (tid == 0)
        inv_s = 1.f / sqrtf((red[0] + red[1] + red[2] + red[3]) * (1.f / DM) + LNEPS);
    __syncthreads();
    const float inv = inv_s;
    float4 gg = *(const float4*)(g + tid * 4);
    float4 bb = *(const float4*)(b + tid * 4);
    v.x = dx * inv * gg.x + bb.x; v.y = dy * inv * gg.y + bb.y;
    v.z = dz * inv * gg.z + bb.z; v.w = dw * inv * gg.w + bb.w;
    *(float4*)p = v;
}

// ---------------- Flash attention, 64x64 tiles, online softmax ----------------
// grid (qtile=16, head=16, batch=2), 256 threads. 4x4 micro per thread.
__global__ __launch_bounds__(256)
void attn_k(const float* __restrict__ Qg, const float* __restrict__ Kg,
            const float* __restrict__ Vg, float* __restrict__ Og)
{
    const int qt = blockIdx.x, hh = blockIdx.y, bb = blockIdx.z;
    __shared__ float Qts[HDIM][68];   // [d][row]
    __shared__ float Kts[HDIM][68];   // [d][key]
    __shared__ float Vs[64][68];      // [key][d]
    __shared__ float Pts[64][68];     // [key][row]
    const int tid = threadIdx.x;
    const int lr = tid >> 2;          // 0..63 loader row
    const int lc = tid & 3;           // 0..3  loader d-chunk
    const int mi = tid >> 4;          // 0..15 -> rows mi*4..+3
    const int ni = tid & 15;          // 0..15 -> cols ni*4..+3
    const int rowbase = bb * SLEN + qt * 64;

    // Q tile -> LDS transposed
    {
        const float* qsrc = Qg + (size_t)(rowbase + lr) * DM + hh * HDIM + lc * 16;
#pragma unroll
        for (int f = 0; f < 4; f++) {
            float4 t = *(const float4*)(qsrc + f * 4);
            int d = lc * 16 + f * 4;
            Qts[d + 0][lr] = t.x; Qts[d + 1][lr] = t.y;
            Qts[d + 2][lr] = t.z; Qts[d + 3][lr] = t.w;
        }
    }
    float o[4][4];
    float m_i[4], l_i[4];
#pragma unroll
    for (int i = 0; i < 4; i++) {
        m_i[i] = -INFINITY; l_i[i] = 0.f;
#pragma unroll
        for (int j = 0; j < 4; j++) o[i][j] = 0.f;
    }

    for (int kt = 0; kt <= qt; kt++) {
        const float* ksrc = Kg + (size_t)(bb * SLEN + kt * 64 + lr) * DM + hh * HDIM + lc * 16;
        const float* vsrc = Vg + (size_t)(bb * SLEN + kt * 64 + lr) * DM + hh * HDIM + lc * 16;
        __syncthreads();   // previous PV phase done before overwriting K/V/P
#pragma unroll
        for (int f = 0; f < 4; f++) {
            float4 t = *(const float4*)(ksrc + f * 4);
            int d = lc * 16 + f * 4;
            Kts[d + 0][lr] = t.x; Kts[d + 1][lr] = t.y;
            Kts[d + 2][lr] = t.z; Kts[d + 3][lr] = t.w;
            float4 u = *(const float4*)(vsrc + f * 4);
            *(float4*)&Vs[lr][lc * 16 + f * 4] = u;
        }
        __syncthreads();

        // scores: c = Q @ K^T * scale
        float c[4][4];
#pragma unroll
        for (int i = 0; i < 4; i++)
#pragma unroll
            for (int j = 0; j < 4; j++) c[i][j] = 0.f;
#pragma unroll 8
        for (int d = 0; d < HDIM; d++) {
            float4 a = *(const float4*)&Qts[d][mi * 4];
            float4 b = *(const float4*)&Kts[d][ni * 4];
            float av[4] = {a.x, a.y, a.z, a.w};
            float bv[4] = {b.x, b.y, b.z, b.w};
#pragma unroll
            for (int i = 0; i < 4; i++)
#pragma unroll
                for (int j = 0; j < 4; j++)
                    c[i][j] = fmaf(av[i], bv[j], c[i][j]);
        }
#pragma unroll
        for (int i = 0; i < 4; i++)
#pragma unroll
            for (int j = 0; j < 4; j++) c[i][j] *= 0.125f;
        if (kt == qt) {
#pragma unroll
            for (int i = 0; i < 4; i++)
#pragma unroll
                for (int j = 0; j < 4; j++)
                    if (ni * 4 + j > mi * 4 + i) c[i][j] = -INFINITY;
        }
        // online softmax update (row groups of 16 lanes share mi)
#pragma unroll
        for (int i = 0; i < 4; i++) {
            float mr = fmaxf(fmaxf(c[i][0], c[i][1]), fmaxf(c[i][2], c[i][3]));
            mr = fmaxf(mr, __shfl_xor(mr, 1));
            mr = fmaxf(mr, __shfl_xor(mr, 2));
            mr = fmaxf(mr, __shfl_xor(mr, 4));
            mr = fmaxf(mr, __shfl_xor(mr, 8));
            float mn = fmaxf(m_i[i], mr);
            float alpha = expf(m_i[i] - mn);   // expf(-inf - finite) = 0
            m_i[i] = mn;
            float rs = 0.f;
#pragma unroll
            for (int j = 0; j < 4; j++) {
                float pv = expf(c[i][j] - mn);
                c[i][j] = pv;
                rs += pv;
            }
            rs += __shfl_xor(rs, 1);
            rs += __shfl_xor(rs, 2);
            rs += __shfl_xor(rs, 4);
            rs += __shfl_xor(rs, 8);
            l_i[i] = l_i[i] * alpha + rs;
#pragma unroll
            for (int j = 0; j < 4; j++) o[i][j] *= alpha;
        }
        // P -> LDS transposed
#pragma unroll
        for (int i = 0; i < 4; i++)
#pragma unroll
            for (int j = 0; j < 4; j++)
                Pts[ni * 4 + j][mi * 4 + i] = c[i][j];
        __syncthreads();
        // O += P @ V
#pragma unroll 8
        for (int kk = 0; kk < 64; kk++) {
            float4 a = *(const float4*)&Pts[kk][mi * 4];
            float4 b = *(const float4*)&Vs[kk][ni * 4];
            float av[4] = {a.x, a.y, a.z, a.w};
            float bv[4] = {b.x, b.y, b.z, b.w};
#pragma unroll
            for (int i = 0; i < 4; i++)
#pragma unroll
                for (int j = 0; j < 4; j++)
                    o[i][j] = fmaf(av[i], bv[j], o[i][j]);
        }
    }
#pragma unroll
    for (int i = 0; i < 4; i++) {
        float inv = 1.f / l_i[i];
        float4 v;
        v.x = o[i][0] * inv; v.y = o[i][1] * inv;
        v.z = o[i][2] * inv; v.w = o[i][3] * inv;
        *(float4*)(Og + (size_t)(rowbase + mi * 4 + i) * DM + hh * HDIM + ni * 4) = v;
    }
}

// ---------------- Router stage 2: rlog = rh @ rW2 + rb2; argmax ----------------
__global__ __launch_bounds__(256)
void router2_k(const float* __restrict__ rh, const float* __restrict__ w,
               const float* __restrict__ b, int* __restrict__ mask,
               int* __restrict__ counts)
{
    const int t = blockIdx.x * 256 + threadIdx.x;
    const float* hr = rh + (size_t)t * RHID;
    float l0 = b[0], l1 = b[1], l2 = b[2];
    for (int kk = 0; kk < RHID; kk++) {
        float hv = hr[kk];
        l0 = fmaf(hv, w[kk * 3 + 0], l0);
        l1 = fmaf(hv, w[kk * 3 + 1], l1);
        l2 = fmaf(hv, w[kk * 3 + 2], l2);
    }
    int a = 0; float best = l0;                 // ties -> lowest index (numpy argmax)
    if (l1 > best) { best = l1; a = 1; }
    if (l2 > best) { best = l2; a = 2; }
    mask[t] = (a == 0);
    atomicAdd(&counts[a], 1);
}

// ---------------- h = skip ? h : ht ----------------
__global__ __launch_bounds__(256)
void select_k(float* __restrict__ h, const float* __restrict__ ht,
              const int* __restrict__ mask)
{
    const int t = blockIdx.x;
    if (mask[t]) return;      // uniform per block
    const int d = threadIdx.x * 4;
    *(float4*)(h + (size_t)t * DM + d) = *(const float4*)(ht + (size_t)t * DM + d);
}

// ---------------- final scalars ----------------
__global__ void scalars_k(const int* __restrict__ counts, float* __restrict__ o)
{
    float c0 = (float)counts[0], c1 = (float)counts[1], c2 = (float)counts[2];
    o[0] = (c1 + c2) / (float)TOK;              // effective_depth
    const float tot = (float)(TOK * NLAY);
    o[1] = c0 / tot; o[2] = c1 / tot; o[3] = c2 / tot;
}

extern "C" void kernel_launch(void* const* d_in, const int* in_sizes, int n_in,
                              void* d_out, int out_size, void* d_ws, size_t ws_size,
                              hipStream_t stream)
{
    (void)in_sizes; (void)n_in; (void)out_size; (void)ws_size;
    const int*   x    = (const int*)d_in[0];
    const float* emb  = (const float*)d_in[1];
    const float* Wq   = (const float*)d_in[2];
    const float* bq   = (const float*)d_in[3];
    const float* Wk   = (const float*)d_in[4];
    const float* bk   = (const float*)d_in[5];
    const float* Wv   = (const float*)d_in[6];
    const float* bv   = (const float*)d_in[7];
    const float* Wo   = (const float*)d_in[8];
    const float* bo   = (const float*)d_in[9];
    const float* ln1g = (const float*)d_in[10];
    const float* ln1b = (const float*)d_in[11];
    const float* Wf1  = (const float*)d_in[12];
    const float* bf1  = (const float*)d_in[13];
    const float* Wf2  = (const float*)d_in[14];
    const float* bf2  = (const float*)d_in[15];
    const float* ln2g = (const float*)d_in[16];
    const float* ln2b = (const float*)d_in[17];
    const float* rW1  = (const float*)d_in[18];
    const float* rb1  = (const float*)d_in[19];
    const float* rW2  = (const float*)d_in[20];
    const float* rb2  = (const float*)d_in[21];
    const float* Wout = (const float*)d_in[22];
    const float* bout = (const float*)d_in[23];
    float* out = (float*)d_out;
    float* ws  = (float*)d_ws;

    // workspace layout (floats)
    float* h   = ws;                       // [2048,1024]
    float* h1  = ws + 2097152;             // [2048,1024]
    float* ab  = ws + 4194304;             // attn out / ht  [2048,1024]
    float* un  = ws + 6291456;             // union: q|k|v (3x2M) OR f1 (8M)
    float* q   = un;
    float* k   = un + 2097152;
    float* v   = un + 4194304;
    float* f1  = un;                       // [2048,4096]
    float* rh  = ws + 14680064;            // [2048,128]
    int*   mask   = (int*)(ws + 14942208); // [2048]
    int*   counts = mask + TOK;            // [3]

    hipMemsetAsync(counts, 0, 3 * sizeof(int), stream);
    emb_k<<<TOK, 256, 0, stream>>>(x, emb, h);

    for (int L = 0; L < NLAY; L++) {
        // router
        gemm_k<1, 0><<<dim3(TOK / 128, RHID / 64), 256, 0, stream>>>(
            h, rW1 + (size_t)L * DM * RHID, rb1 + L * RHID, nullptr, rh, TOK, RHID, DM);
        router2_k<<<TOK / 256, 256, 0, stream>>>(
            rh, rW2 + (size_t)L * RHID * 3, rb2 + L * 3, mask, counts);
        // QKV
        gemm_k<0, 0><<<dim3(TOK / 128, DM / 64), 256, 0, stream>>>(h, Wq, bq, nullptr, q, TOK, DM, DM);
        gemm_k<0, 0><<<dim3(TOK / 128, DM / 64), 256, 0, stream>>>(h, Wk, bk, nullptr, k, TOK, DM, DM);
        gemm_k<0, 0><<<dim3(TOK / 128, DM / 64), 256, 0, stream>>>(h, Wv, bv, nullptr, v, TOK, DM, DM);
        // attention
        attn_k<<<dim3(SLEN / 64, NHEAD, 2), 256, 0, stream>>>(q, k, v, ab);
        // out proj + residual, then LN1
        gemm_k<0, 1><<<dim3(TOK / 128, DM / 64), 256, 0, stream>>>(ab, Wo, bo, h, h1, TOK, DM, DM);
        ln_k<<<TOK, 256, 0, stream>>>(h1, ln1g, ln1b);
        // FFN
        gemm_k<1, 0><<<dim3(TOK / 128, DFFN / 64), 256, 0, stream>>>(h1, Wf1, bf1, nullptr, f1, TOK, DFFN, DM);
        gemm_k<0, 1><<<dim3(TOK / 128, DM / 64), 256, 0, stream>>>(f1, Wf2, bf2, h1, ab, TOK, DM, DFFN);
        ln_k<<<TOK, 256, 0, stream>>>(ab, ln2g, ln2b);
        // h = skip ? h : ht
        select_k<<<TOK, 256, 0, stream>>>(h, ab, mask);
    }

    // logits
    gemm_k<0, 0><<<dim3(TOK / 128, NVOCAB / 64), 256, 0, stream>>>(
        h, Wout, bout, nullptr, out, TOK, NVOCAB, DM);
    scalars_k<<<1, 1, 0, stream>>>(counts, out + (size_t)TOK * NVOCAB);
}

// Round 2
// 8664.417 us; speedup vs baseline: 1.7677x; 1.7677x over previous
//
#include <hip/hip_runtime.h>
#include <hip/hip_bf16.h>
#include <math.h>

#define TOK     2048
#define DM      1024
#define SLEN    1024
#define NHEAD   16
#define HDIM    64
#define DFFN    4096
#define RHID    128
#define NLAY    12
#define NVOCAB  32000
#define LNEPS   1e-5f

typedef __bf16 bf16x8 __attribute__((ext_vector_type(8)));
typedef float  f32x4  __attribute__((ext_vector_type(4)));

union bf4u { __hip_bfloat16 b[4]; ushort4 u; };

__device__ __forceinline__ void split2(float v, __hip_bfloat16& hi, __hip_bfloat16& lo) {
    hi = __float2bfloat16(v);
    lo = __float2bfloat16(v - __bfloat162float(hi));
}

#define GLL(gp, lp) __builtin_amdgcn_global_load_lds(                          \
    (const __attribute__((address_space(1))) void*)(gp),                       \
    (__attribute__((address_space(3))) void*)(lp), 16, 0, 0)

// ============================================================================
// bf16x2-split MFMA GEMM: C[M,N] = act(A@B + bias (+Rsd)), A=[M,K] hi/lo bf16,
// B given TRANSPOSED [N,K] hi/lo bf16. 128x128 tile, BK=32, 256 thr (4 waves).
// OUTMODE 0: fp32 C.  OUTMODE 1: split bf16 (Ch,Cl).
// ============================================================================
template<int OUTMODE, int RELU, int RES>
__global__ __launch_bounds__(256)
void mgemm_k(const __hip_bfloat16* __restrict__ Ah, const __hip_bfloat16* __restrict__ Al,
             const __hip_bfloat16* __restrict__ Bh, const __hip_bfloat16* __restrict__ Bl,
             const float* __restrict__ bias, const float* __restrict__ Rsd,
             float* __restrict__ C, __hip_bfloat16* __restrict__ Ch,
             __hip_bfloat16* __restrict__ Cl, int M, int N, int K)
{
    __shared__ __align__(16) __hip_bfloat16 sA[2][128 * 32];
    __shared__ __align__(16) __hip_bfloat16 sB[2][128 * 32];
    const int tid  = threadIdx.x;
    const int lane = tid & 63, wave = tid >> 6;
    const int m0 = blockIdx.x * 128, n0 = blockIdx.y * 128;
    const int wm = (wave & 1) * 64, wn = (wave >> 1) * 64;

    f32x4 acc[4][4];
#pragma unroll
    for (int i = 0; i < 4; i++)
#pragma unroll
        for (int j = 0; j < 4; j++) acc[i][j] = (f32x4){0.f, 0.f, 0.f, 0.f};

    // staging granule assignment (granule = 16B = 8 bf16); swizzled layout:
    // lds granule(row,g) = row*4 + (g ^ ((row>>1)&3))
    const int G0 = wave * 64 + lane;
    const int G1 = G0 + 256;
    const int rA0 = G0 >> 2, gA0 = (G0 & 3) ^ ((rA0 >> 1) & 3);
    const int rA1 = G1 >> 2, gA1 = (G1 & 3) ^ ((rA1 >> 1) & 3);

    const char* pA0h = (const char*)(Ah + (size_t)(m0 + rA0) * K + gA0 * 8);
    const char* pA1h = (const char*)(Ah + (size_t)(m0 + rA1) * K + gA1 * 8);
    const char* pA0l = (const char*)(Al + (size_t)(m0 + rA0) * K + gA0 * 8);
    const char* pA1l = (const char*)(Al + (size_t)(m0 + rA1) * K + gA1 * 8);
    const char* pB0h = (const char*)(Bh + (size_t)(n0 + rA0) * K + gA0 * 8);
    const char* pB1h = (const char*)(Bh + (size_t)(n0 + rA1) * K + gA1 * 8);
    const char* pB0l = (const char*)(Bl + (size_t)(n0 + rA0) * K + gA0 * 8);
    const char* pB1l = (const char*)(Bl + (size_t)(n0 + rA1) * K + gA1 * 8);

    __hip_bfloat16* dA0h = &sA[0][G0 * 8]; __hip_bfloat16* dA1h = &sA[0][G1 * 8];
    __hip_bfloat16* dA0l = &sA[1][G0 * 8]; __hip_bfloat16* dA1l = &sA[1][G1 * 8];
    __hip_bfloat16* dB0h = &sB[0][G0 * 8]; __hip_bfloat16* dB1h = &sB[0][G1 * 8];
    __hip_bfloat16* dB0l = &sB[1][G0 * 8]; __hip_bfloat16* dB1l = &sB[1][G1 * 8];

    const int q = lane >> 4, r = lane & 15;

    for (int k0 = 0; k0 < K; k0 += 32) {
        __syncthreads();
        GLL(pA0h, dA0h); GLL(pA1h, dA1h);
        GLL(pA0l, dA0l); GLL(pA1l, dA1l);
        GLL(pB0h, dB0h); GLL(pB1h, dB1h);
        GLL(pB0l, dB0l); GLL(pB1l, dB1l);
        pA0h += 64; pA1h += 64; pA0l += 64; pA1l += 64;
        pB0h += 64; pB1h += 64; pB0l += 64; pB1l += 64;
        __syncthreads();

        bf16x8 fah[4], fal[4], fbh[4], fbl[4];
#pragma unroll
        for (int mt = 0; mt < 4; mt++) {
            int row = wm + mt * 16 + r;
            int gi = (row * 4 + (q ^ ((row >> 1) & 3))) * 8;
            fah[mt] = *(const bf16x8*)&sA[0][gi];
            fal[mt] = *(const bf16x8*)&sA[1][gi];
        }
#pragma unroll
        for (int nt = 0; nt < 4; nt++) {
            int col = wn + nt * 16 + r;
            int gi = (col * 4 + (q ^ ((col >> 1) & 3))) * 8;
            fbh[nt] = *(const bf16x8*)&sB[0][gi];
            fbl[nt] = *(const bf16x8*)&sB[1][gi];
        }
#pragma unroll
        for (int mt = 0; mt < 4; mt++)
#pragma unroll
            for (int nt = 0; nt < 4; nt++) {
                acc[mt][nt] = __builtin_amdgcn_mfma_f32_16x16x32_bf16(fah[mt], fbh[nt], acc[mt][nt], 0, 0, 0);
                acc[mt][nt] = __builtin_amdgcn_mfma_f32_16x16x32_bf16(fal[mt], fbh[nt], acc[mt][nt], 0, 0, 0);
                acc[mt][nt] = __builtin_amdgcn_mfma_f32_16x16x32_bf16(fah[mt], fbl[nt], acc[mt][nt], 0, 0, 0);
            }
    }

    // epilogue: C/D layout col=lane&15, row=(lane>>4)*4+reg
    float bv[4];
#pragma unroll
    for (int nt = 0; nt < 4; nt++) bv[nt] = bias[n0 + wn + nt * 16 + r];
#pragma unroll
    for (int mt = 0; mt < 4; mt++)
#pragma unroll
        for (int rr = 0; rr < 4; rr++) {
            const size_t row = (size_t)(m0 + wm + mt * 16 + q * 4 + rr);
#pragma unroll
            for (int nt = 0; nt < 4; nt++) {
                const int col = n0 + wn + nt * 16 + r;
                float v = acc[mt][nt][rr] + bv[nt];
                if (RES) v += Rsd[row * N + col];
                if (RELU) v = fmaxf(v, 0.f);
                if (OUTMODE == 0) {
                    C[row * N + col] = v;
                } else {
                    __hip_bfloat16 hi, lo;
                    split2(v, hi, lo);
                    Ch[row * N + col] = hi;
                    Cl[row * N + col] = lo;
                }
            }
        }
}

// ============================================================================
// weight split + transpose: W[K,N] fp32 -> Th,Tl[N,K] bf16 hi/lo
// ============================================================================
__global__ __launch_bounds__(256)
void splitw_k(const float* __restrict__ W, __hip_bfloat16* __restrict__ Th,
              __hip_bfloat16* __restrict__ Tl, int K, int N)
{
    __shared__ float t[32][33];
    const int k0 = blockIdx.x * 32, n0 = blockIdx.y * 32;
    const int rr = threadIdx.x >> 3, c4 = (threadIdx.x & 7) * 4;
    float4 vv = *(const float4*)(W + (size_t)(k0 + rr) * N + n0 + c4);
    t[rr][c4 + 0] = vv.x; t[rr][c4 + 1] = vv.y;
    t[rr][c4 + 2] = vv.z; t[rr][c4 + 3] = vv.w;
    __syncthreads();
    bf4u hu, lu;
#pragma unroll
    for (int u = 0; u < 4; u++)
        split2(t[c4 + u][rr], hu.b[u], lu.b[u]);
    size_t o = (size_t)(n0 + rr) * K + k0 + c4;
    *(ushort4*)&Th[o] = hu.u;
    *(ushort4*)&Tl[o] = lu.u;
}

// ============================================================================
// legacy fp32 GEMM (fallback path)
// ============================================================================
template<int RELU, int RES>
__global__ __launch_bounds__(256)
void gemm_k(const float* __restrict__ A, const float* __restrict__ B,
            const float* __restrict__ bias, const float* __restrict__ Rsd,
            float* __restrict__ C, int M, int N, int K)
{
    constexpr int BM = 128, BN = 64, BK = 16;
    __shared__ float As[BK][BM];
    __shared__ float Bs[BK][BN + 4];
    const int tid = threadIdx.x;
    const int m0 = blockIdx.x * BM;
    const int n0 = blockIdx.y * BN;
    const int mi = tid >> 4, ni = tid & 15;
    const int ar = tid >> 1, ac = (tid & 1) * 8;
    const int br = tid >> 4, bc = (tid & 15) * 4;
    const float* Arow = A + (size_t)(m0 + ar) * K + ac;
    float acc[8][4];
#pragma unroll
    for (int i = 0; i < 8; i++)
#pragma unroll
        for (int j = 0; j < 4; j++) acc[i][j] = 0.f;
    for (int k0 = 0; k0 < K; k0 += BK) {
        float4 a0 = *(const float4*)(Arow + k0);
        float4 a1 = *(const float4*)(Arow + k0 + 4);
        float4 b0 = *(const float4*)(B + (size_t)(k0 + br) * N + n0 + bc);
        __syncthreads();
        As[ac + 0][ar] = a0.x; As[ac + 1][ar] = a0.y;
        As[ac + 2][ar] = a0.z; As[ac + 3][ar] = a0.w;
        As[ac + 4][ar] = a1.x; As[ac + 5][ar] = a1.y;
        As[ac + 6][ar] = a1.z; As[ac + 7][ar] = a1.w;
        *(float4*)&Bs[br][bc] = b0;
        __syncthreads();
#pragma unroll
        for (int kk = 0; kk < BK; kk++) {
            float a[8], b[4];
            *(float4*)&a[0] = *(const float4*)&As[kk][mi * 8];
            *(float4*)&a[4] = *(const float4*)&As[kk][mi * 8 + 4];
            *(float4*)&b[0] = *(const float4*)&Bs[kk][ni * 4];
#pragma unroll
            for (int i = 0; i < 8; i++)
#pragma unroll
                for (int j = 0; j < 4; j++)
                    acc[i][j] = fmaf(a[i], b[j], acc[i][j]);
        }
    }
    const int nn = n0 + ni * 4;
    float4 bi = *(const float4*)&bias[nn];
#pragma unroll
    for (int i = 0; i < 8; i++) {
        const size_t m = (size_t)(m0 + mi * 8 + i);
        float4 v;
        v.x = acc[i][0] + bi.x; v.y = acc[i][1] + bi.y;
        v.z = acc[i][2] + bi.z; v.w = acc[i][3] + bi.w;
        if (RES) {
            float4 rr = *(const float4*)(Rsd + m * N + nn);
            v.x += rr.x; v.y += rr.y; v.z += rr.z; v.w += rr.w;
        }
        if (RELU) {
            v.x = fmaxf(v.x, 0.f); v.y = fmaxf(v.y, 0.f);
            v.z = fmaxf(v.z, 0.f); v.w = fmaxf(v.w, 0.f);
        }
        *(float4*)(C + m * N + nn) = v;
    }
}

// ---------------- Embedding + positional encoding ----------------
template<int SPLIT>
__global__ __launch_bounds__(256)
void emb_k(const int* __restrict__ x, const float* __restrict__ emb,
           float* __restrict__ h, __hip_bfloat16* __restrict__ Hh,
           __hip_bfloat16* __restrict__ Hl)
{
    const int t = blockIdx.x;
    const int s = t & (SLEN - 1);
    const int d0 = threadIdx.x * 4;
    const int tokid = x[t];
    float4 e = *(const float4*)(emb + (size_t)tokid * DM + d0);
    const float po = (float)s;
    const float fac = -9.210340371976184f / 1024.f;
    float pe[4];
#pragma unroll
    for (int u = 0; u < 4; u++) {
        int d = d0 + u;
        float freq = expf(fac * (float)(d & ~1));
        pe[u] = (d & 1) ? cosf(po * freq) : sinf(po * freq);
    }
    float4 rv;
    rv.x = e.x * 32.f + pe[0]; rv.y = e.y * 32.f + pe[1];
    rv.z = e.z * 32.f + pe[2]; rv.w = e.w * 32.f + pe[3];
    const size_t idx = (size_t)t * DM + d0;
    *(float4*)(h + idx) = rv;
    if constexpr (SPLIT) {
        bf4u hu, lu;
        split2(rv.x, hu.b[0], lu.b[0]); split2(rv.y, hu.b[1], lu.b[1]);
        split2(rv.z, hu.b[2], lu.b[2]); split2(rv.w, hu.b[3], lu.b[3]);
        *(ushort4*)&Hh[idx] = hu.u;
        *(ushort4*)&Hl[idx] = lu.u;
    }
}

// ---------------- LayerNorm (in place) ----------------
template<int SPLIT>
__global__ __launch_bounds__(256)
void ln_k(float* __restrict__ H, const float* __restrict__ g,
          const float* __restrict__ b, __hip_bfloat16* __restrict__ Ch,
          __hip_bfloat16* __restrict__ Cl)
{
    const int row = blockIdx.x, tid = threadIdx.x;
    float* p = H + (size_t)row * DM + tid * 4;
    float4 v = *(float4*)p;
    __shared__ float red[4];
    __shared__ float mean_s, inv_s;
    float s = v.x + v.y + v.z + v.w;
#pragma unroll
    for (int off = 32; off; off >>= 1) s += __shfl_down(s, off);
    if ((tid & 63) == 0) red[tid >> 6] = s;
    __syncthreads();
    if (tid == 0) mean_s = (red[0] + red[1] + red[2] + red[3]) * (1.f / DM);
    __syncthreads();
    const float mu = mean_s;
    float dx = v.x - mu, dy = v.y - mu, dz = v.z - mu, dw = v.w - mu;
    float qq = dx * dx + dy * dy + dz * dz + dw * dw;
#pragma unroll
    for (int off = 32; off; off >>= 1) qq += __shfl_down(qq, off);
    if ((tid & 63) == 0) red[tid >> 6] = qq;
    __syncthreads();
    if (tid == 0)
        inv_s = 1.f / sqrtf((red[0] + red[1] + red[2] + red[3]) * (1.f / DM) + LNEPS);
    __syncthreads();
    const float inv = inv_s;
    float4 gg = *(const float4*)(g + tid * 4);
    float4 bb = *(const float4*)(b + tid * 4);
    v.x = dx * inv * gg.x + bb.x; v.y = dy * inv * gg.y + bb.y;
    v.z = dz * inv * gg.z + bb.z; v.w = dw * inv * gg.w + bb.w;
    *(float4*)p = v;
    if constexpr (SPLIT) {
        bf4u hu, lu;
        split2(v.x, hu.b[0], lu.b[0]); split2(v.y, hu.b[1], lu.b[1]);
        split2(v.z, hu.b[2], lu.b[2]); split2(v.w, hu.b[3], lu.b[3]);
        const size_t idx = (size_t)row * DM + tid * 4;
        *(ushort4*)&Ch[idx] = hu.u;
        *(ushort4*)&Cl[idx] = lu.u;
    }
}

// ---------------- Flash attention (fp32), optional split output ----------------
template<int SPLIT>
__global__ __launch_bounds__(256)
void attn_k(const float* __restrict__ Qg, const float* __restrict__ Kg,
            const float* __restrict__ Vg, float* __restrict__ Og,
            __hip_bfloat16* __restrict__ Oh, __hip_bfloat16* __restrict__ Ol)
{
    const int qt = blockIdx.x, hh = blockIdx.y, bb = blockIdx.z;
    __shared__ float Qts[HDIM][68];
    __shared__ float Kts[HDIM][68];
    __shared__ float Vs[64][68];
    __shared__ float Pts[64][68];
    const int tid = threadIdx.x;
    const int lr = tid >> 2, lc = tid & 3;
    const int mi = tid >> 4, ni = tid & 15;
    const int rowbase = bb * SLEN + qt * 64;
    {
        const float* qsrc = Qg + (size_t)(rowbase + lr) * DM + hh * HDIM + lc * 16;
#pragma unroll
        for (int f = 0; f < 4; f++) {
            float4 t = *(const float4*)(qsrc + f * 4);
            int d = lc * 16 + f * 4;
            Qts[d + 0][lr] = t.x; Qts[d + 1][lr] = t.y;
            Qts[d + 2][lr] = t.z; Qts[d + 3][lr] = t.w;
        }
    }
    float o[4][4];
    float m_i[4], l_i[4];
#pragma unroll
    for (int i = 0; i < 4; i++) {
        m_i[i] = -INFINITY; l_i[i] = 0.f;
#pragma unroll
        for (int j = 0; j < 4; j++) o[i][j] = 0.f;
    }
    for (int kt = 0; kt <= qt; kt++) {
        const float* ksrc = Kg + (size_t)(bb * SLEN + kt * 64 + lr) * DM + hh * HDIM + lc * 16;
        const float* vsrc = Vg + (size_t)(bb * SLEN + kt * 64 + lr) * DM + hh * HDIM + lc * 16;
        __syncthreads();
#pragma unroll
        for (int f = 0; f < 4; f++) {
            float4 t = *(const float4*)(ksrc + f * 4);
            int d = lc * 16 + f * 4;
            Kts[d + 0][lr] = t.x; Kts[d + 1][lr] = t.y;
            Kts[d + 2][lr] = t.z; Kts[d + 3][lr] = t.w;
            float4 u = *(const float4*)(vsrc + f * 4);
            *(float4*)&Vs[lr][lc * 16 + f * 4] = u;
        }
        __syncthreads();
        float c[4][4];
#pragma unroll
        for (int i = 0; i < 4; i++)
#pragma unroll
            for (int j = 0; j < 4; j++) c[i][j] = 0.f;
#pragma unroll 8
        for (int d = 0; d < HDIM; d++) {
            float4 a = *(const float4*)&Qts[d][mi * 4];
            float4 b = *(const float4*)&Kts[d][ni * 4];
            float av[4] = {a.x, a.y, a.z, a.w};
            float bv[4] = {b.x, b.y, b.z, b.w};
#pragma unroll
            for (int i = 0; i < 4; i++)
#pragma unroll
                for (int j = 0; j < 4; j++)
                    c[i][j] = fmaf(av[i], bv[j], c[i][j]);
        }
#pragma unroll
        for (int i = 0; i < 4; i++)
#pragma unroll
            for (int j = 0; j < 4; j++) c[i][j] *= 0.125f;
        if (kt == qt) {
#pragma unroll
            for (int i = 0; i < 4; i++)
#pragma unroll
                for (int j = 0; j < 4; j++)
                    if (ni * 4 + j > mi * 4 + i) c[i][j] = -INFINITY;
        }
#pragma unroll
        for (int i = 0; i < 4; i++) {
            float mr = fmaxf(fmaxf(c[i][0], c[i][1]), fmaxf(c[i][2], c[i][3]));
            mr = fmaxf(mr, __shfl_xor(mr, 1));
            mr = fmaxf(mr, __shfl_xor(mr, 2));
            mr = fmaxf(mr, __shfl_xor(mr, 4));
            mr = fmaxf(mr, __shfl_xor(mr, 8));
            float mn = fmaxf(m_i[i], mr);
            float alpha = expf(m_i[i] - mn);
            m_i[i] = mn;
            float rs = 0.f;
#pragma unroll
            for (int j = 0; j < 4; j++) {
                float pv = expf(c[i][j] - mn);
                c[i][j] = pv;
                rs += pv;
            }
            rs += __shfl_xor(rs, 1);
            rs += __shfl_xor(rs, 2);
            rs += __shfl_xor(rs, 4);
            rs += __shfl_xor(rs, 8);
            l_i[i] = l_i[i] * alpha + rs;
#pragma unroll
            for (int j = 0; j < 4; j++) o[i][j] *= alpha;
        }
#pragma unroll
        for (int i = 0; i < 4; i++)
#pragma unroll
            for (int j = 0; j < 4; j++)
                Pts[ni * 4 + j][mi * 4 + i] = c[i][j];
        __syncthreads();
#pragma unroll 8
        for (int kk = 0; kk < 64; kk++) {
            float4 a = *(const float4*)&Pts[kk][mi * 4];
            float4 b = *(const float4*)&Vs[kk][ni * 4];
            float av[4] = {a.x, a.y, a.z, a.w};
            float bv[4] = {b.x, b.y, b.z, b.w};
#pragma unroll
            for (int i = 0; i < 4; i++)
#pragma unroll
                for (int j = 0; j < 4; j++)
                    o[i][j] = fmaf(av[i], bv[j], o[i][j]);
        }
    }
#pragma unroll
    for (int i = 0; i < 4; i++) {
        float inv = 1.f / l_i[i];
        const size_t idx = (size_t)(rowbase + mi * 4 + i) * DM + hh * HDIM + ni * 4;
        if constexpr (SPLIT) {
            bf4u hu, lu;
#pragma unroll
            for (int j = 0; j < 4; j++)
                split2(o[i][j] * inv, hu.b[j], lu.b[j]);
            *(ushort4*)&Oh[idx] = hu.u;
            *(ushort4*)&Ol[idx] = lu.u;
        } else {
            float4 v;
            v.x = o[i][0] * inv; v.y = o[i][1] * inv;
            v.z = o[i][2] * inv; v.w = o[i][3] * inv;
            *(float4*)(Og + idx) = v;
        }
    }
}

// ---------------- fused router: rh=relu(h@W1+b1); rlog=rh@W2+b2; argmax ----------------
// grid 256 blocks x 256 thr; block = 8 tokens; thread: token tid>>5, cols (tid&31)*4..+3
__global__ __launch_bounds__(256)
void rtr_k(const float* __restrict__ h, const float* __restrict__ W1,
           const float* __restrict__ b1, const float* __restrict__ W2,
           const float* __restrict__ b2, int* __restrict__ mask,
           int* __restrict__ counts)
{
    const int tid = threadIdx.x;
    const int tok = blockIdx.x * 8 + (tid >> 5);
    const int cg = tid & 31;
    const float* hrow = h + (size_t)tok * DM;
    float a0 = b1[cg * 4 + 0], a1 = b1[cg * 4 + 1];
    float a2 = b1[cg * 4 + 2], a3 = b1[cg * 4 + 3];
#pragma unroll 4
    for (int kk = 0; kk < DM; kk++) {
        float hv = hrow[kk];
        float4 w = *(const float4*)(W1 + (size_t)kk * RHID + cg * 4);
        a0 = fmaf(hv, w.x, a0); a1 = fmaf(hv, w.y, a1);
        a2 = fmaf(hv, w.z, a2); a3 = fmaf(hv, w.w, a3);
    }
    a0 = fmaxf(a0, 0.f); a1 = fmaxf(a1, 0.f);
    a2 = fmaxf(a2, 0.f); a3 = fmaxf(a3, 0.f);
    float l0, l1, l2;
    {
        const float* w0 = W2 + (size_t)(cg * 4) * 3;
        l0 = a0 * w0[0] + a1 * w0[3] + a2 * w0[6] + a3 * w0[9];
        l1 = a0 * w0[1] + a1 * w0[4] + a2 * w0[7] + a3 * w0[10];
        l2 = a0 * w0[2] + a1 * w0[5] + a2 * w0[8] + a3 * w0[11];
    }
#pragma unroll
    for (int off = 1; off < 32; off <<= 1) {
        l0 += __shfl_xor(l0, off);
        l1 += __shfl_xor(l1, off);
        l2 += __shfl_xor(l2, off);
    }
    if (cg == 0) {
        l0 += b2[0]; l1 += b2[1]; l2 += b2[2];
        int a = 0; float best = l0;
        if (l1 > best) { best = l1; a = 1; }
        if (l2 > best) { best = l2; a = 2; }
        mask[tok] = (a == 0);
        atomicAdd(&counts[a], 1);
    }
}

// legacy router stage2 (fallback)
__global__ __launch_bounds__(256)
void router2_k(const float* __restrict__ rh, const float* __restrict__ w,
               const float* __restrict__ b, int* __restrict__ mask,
               int* __restrict__ counts)
{
    const int t = blockIdx.x * 256 + threadIdx.x;
    const float* hr = rh + (size_t)t * RHID;
    float l0 = b[0], l1 = b[1], l2 = b[2];
    for (int kk = 0; kk < RHID; kk++) {
        float hv = hr[kk];
        l0 = fmaf(hv, w[kk * 3 + 0], l0);
        l1 = fmaf(hv, w[kk * 3 + 1], l1);
        l2 = fmaf(hv, w[kk * 3 + 2], l2);
    }
    int a = 0; float best = l0;
    if (l1 > best) { best = l1; a = 1; }
    if (l2 > best) { best = l2; a = 2; }
    mask[t] = (a == 0);
    atomicAdd(&counts[a], 1);
}

// ---------------- h = skip ? h : ht (+ optional split refresh) ----------------
template<int SPLIT>
__global__ __launch_bounds__(256)
void select_k(float* __restrict__ h, const float* __restrict__ ht,
              const int* __restrict__ mask, __hip_bfloat16* __restrict__ Hh,
              __hip_bfloat16* __restrict__ Hl)
{
    const int t = blockIdx.x;
    if (mask[t]) return;
    const int d = threadIdx.x * 4;
    const size_t idx = (size_t)t * DM + d;
    float4 v = *(const float4*)(ht + idx);
    *(float4*)(h + idx) = v;
    if constexpr (SPLIT) {
        bf4u hu, lu;
        split2(v.x, hu.b[0], lu.b[0]); split2(v.y, hu.b[1], lu.b[1]);
        split2(v.z, hu.b[2], lu.b[2]); split2(v.w, hu.b[3], lu.b[3]);
        *(ushort4*)&Hh[idx] = hu.u;
        *(ushort4*)&Hl[idx] = lu.u;
    }
}

__global__ void scalars_k(const int* __restrict__ counts, float* __restrict__ o)
{
    float c0 = (float)counts[0], c1 = (float)counts[1], c2 = (float)counts[2];
    o[0] = (c1 + c2) / (float)TOK;
    const float tot = (float)(TOK * NLAY);
    o[1] = c0 / tot; o[2] = c1 / tot; o[3] = c2 / tot;
}

extern "C" void kernel_launch(void* const* d_in, const int* in_sizes, int n_in,
                              void* d_out, int out_size, void* d_ws, size_t ws_size,
                              hipStream_t stream)
{
    (void)in_sizes; (void)n_in; (void)out_size;
    const int*   x    = (const int*)d_in[0];
    const float* emb  = (const float*)d_in[1];
    const float* Wq   = (const float*)d_in[2];
    const float* bq   = (const float*)d_in[3];
    const float* Wk   = (const float*)d_in[4];
    const float* bk   = (const float*)d_in[5];
    const float* Wv   = (const float*)d_in[6];
    const float* bv   = (const float*)d_in[7];
    const float* Wo   = (const float*)d_in[8];
    const float* bo   = (const float*)d_in[9];
    const float* ln1g = (const float*)d_in[10];
    const float* ln1b = (const float*)d_in[11];
    const float* Wf1  = (const float*)d_in[12];
    const float* bf1  = (const float*)d_in[13];
    const float* Wf2  = (const float*)d_in[14];
    const float* bf2  = (const float*)d_in[15];
    const float* ln2g = (const float*)d_in[16];
    const float* ln2b = (const float*)d_in[17];
    const float* rW1  = (const float*)d_in[18];
    const float* rb1  = (const float*)d_in[19];
    const float* rW2  = (const float*)d_in[20];
    const float* rb2  = (const float*)d_in[21];
    const float* Wout = (const float*)d_in[22];
    const float* bout = (const float*)d_in[23];
    float* out = (float*)d_out;
    char*  wsb = (char*)d_ws;

    const size_t MiB = 1048576;
    const size_t REQ = 280 * MiB;

    if (ws_size >= REQ) {
        // ---------- split-precision MFMA path ----------
        float* h   = (float*)(wsb + 0 * MiB);
        float* h1  = (float*)(wsb + 8 * MiB);
        float* ht  = (float*)(wsb + 16 * MiB);
        float* q   = (float*)(wsb + 24 * MiB);
        float* k   = (float*)(wsb + 32 * MiB);
        float* v   = (float*)(wsb + 40 * MiB);
        __hip_bfloat16* hsh  = (__hip_bfloat16*)(wsb + 48 * MiB);
        __hip_bfloat16* hsl  = (__hip_bfloat16*)(wsb + 52 * MiB);
        __hip_bfloat16* h1sh = (__hip_bfloat16*)(wsb + 56 * MiB);
        __hip_bfloat16* h1sl = (__hip_bfloat16*)(wsb + 60 * MiB);
        __hip_bfloat16* absh = (__hip_bfloat16*)(wsb + 64 * MiB);
        __hip_bfloat16* absl = (__hip_bfloat16*)(wsb + 68 * MiB);
        __hip_bfloat16* f1sh = (__hip_bfloat16*)(wsb + 72 * MiB);
        __hip_bfloat16* f1sl = (__hip_bfloat16*)(wsb + 88 * MiB);
        __hip_bfloat16* wqh  = (__hip_bfloat16*)(wsb + 104 * MiB);
        __hip_bfloat16* wql  = (__hip_bfloat16*)(wsb + 106 * MiB);
        __hip_bfloat16* wkh  = (__hip_bfloat16*)(wsb + 108 * MiB);
        __hip_bfloat16* wkl  = (__hip_bfloat16*)(wsb + 110 * MiB);
        __hip_bfloat16* wvh  = (__hip_bfloat16*)(wsb + 112 * MiB);
        __hip_bfloat16* wvl  = (__hip_bfloat16*)(wsb + 114 * MiB);
        __hip_bfloat16* woh  = (__hip_bfloat16*)(wsb + 116 * MiB);
        __hip_bfloat16* wol  = (__hip_bfloat16*)(wsb + 118 * MiB);
        __hip_bfloat16* wf1h = (__hip_bfloat16*)(wsb + 120 * MiB);
        __hip_bfloat16* wf1l = (__hip_bfloat16*)(wsb + 128 * MiB);
        __hip_bfloat16* wf2h = (__hip_bfloat16*)(wsb + 136 * MiB);
        __hip_bfloat16* wf2l = (__hip_bfloat16*)(wsb + 144 * MiB);
        __hip_bfloat16* wouth= (__hip_bfloat16*)(wsb + 152 * MiB);
        __hip_bfloat16* woutl= (__hip_bfloat16*)(wsb + 215 * MiB);
        int* mask   = (int*)(wsb + 278 * MiB);
        int* counts = mask + TOK;

        hipMemsetAsync(counts, 0, 3 * sizeof(int), stream);
        splitw_k<<<dim3(32, 32), 256, 0, stream>>>(Wq, wqh, wql, DM, DM);
        splitw_k<<<dim3(32, 32), 256, 0, stream>>>(Wk, wkh, wkl, DM, DM);
        splitw_k<<<dim3(32, 32), 256, 0, stream>>>(Wv, wvh, wvl, DM, DM);
        splitw_k<<<dim3(32, 32), 256, 0, stream>>>(Wo, woh, wol, DM, DM);
        splitw_k<<<dim3(32, 128), 256, 0, stream>>>(Wf1, wf1h, wf1l, DM, DFFN);
        splitw_k<<<dim3(128, 32), 256, 0, stream>>>(Wf2, wf2h, wf2l, DFFN, DM);
        splitw_k<<<dim3(32, 1000), 256, 0, stream>>>(Wout, wouth, woutl, DM, NVOCAB);
        emb_k<1><<<TOK, 256, 0, stream>>>(x, emb, h, hsh, hsl);

        for (int L = 0; L < NLAY; L++) {
            rtr_k<<<TOK / 8, 256, 0, stream>>>(
                h, rW1 + (size_t)L * DM * RHID, rb1 + L * RHID,
                rW2 + (size_t)L * RHID * 3, rb2 + L * 3, mask, counts);
            mgemm_k<0, 0, 0><<<dim3(16, 8), 256, 0, stream>>>(
                hsh, hsl, wqh, wql, bq, nullptr, q, nullptr, nullptr, TOK, DM, DM);
            mgemm_k<0, 0, 0><<<dim3(16, 8), 256, 0, stream>>>(
                hsh, hsl, wkh, wkl, bk, nullptr, k, nullptr, nullptr, TOK, DM, DM);
            mgemm_k<0, 0, 0><<<dim3(16, 8), 256, 0, stream>>>(
                hsh, hsl, wvh, wvl, bv, nullptr, v, nullptr, nullptr, TOK, DM, DM);
            attn_k<1><<<dim3(SLEN / 64, NHEAD, 2), 256, 0, stream>>>(
                q, k, v, nullptr, absh, absl);
            mgemm_k<0, 0, 1><<<dim3(16, 8), 256, 0, stream>>>(
                absh, absl, woh, wol, bo, h, h1, nullptr, nullptr, TOK, DM, DM);
            ln_k<1><<<TOK, 256, 0, stream>>>(h1, ln1g, ln1b, h1sh, h1sl);
            mgemm_k<1, 1, 0><<<dim3(16, 32), 256, 0, stream>>>(
                h1sh, h1sl, wf1h, wf1l, bf1, nullptr, nullptr, f1sh, f1sl, TOK, DFFN, DM);
            mgemm_k<0, 0, 1><<<dim3(16, 8), 256, 0, stream>>>(
                f1sh, f1sl, wf2h, wf2l, bf2, h1, ht, nullptr, nullptr, TOK, DM, DFFN);
            ln_k<0><<<TOK, 256, 0, stream>>>(ht, ln2g, ln2b, nullptr, nullptr);
            select_k<1><<<TOK, 256, 0, stream>>>(h, ht, mask, hsh, hsl);
        }
        mgemm_k<0, 0, 0><<<dim3(16, 250), 256, 0, stream>>>(
            hsh, hsl, wouth, woutl, bout, nullptr, out, nullptr, nullptr, TOK, NVOCAB, DM);
        scalars_k<<<1, 1, 0, stream>>>(counts, out + (size_t)TOK * NVOCAB);
    } else {
        // ---------- fallback: round-1 fp32 vector path ----------
        float* ws  = (float*)d_ws;
        float* h   = ws;
        float* h1  = ws + 2097152;
        float* ab  = ws + 4194304;
        float* un  = ws + 6291456;
        float* q   = un;
        float* k   = un + 2097152;
        float* v   = un + 4194304;
        float* f1  = un;
        float* rh  = ws + 14680064;
        int*   mask   = (int*)(ws + 14942208);
        int*   counts = mask + TOK;

        hipMemsetAsync(counts, 0, 3 * sizeof(int), stream);
        emb_k<0><<<TOK, 256, 0, stream>>>(x, emb, h, nullptr, nullptr);
        for (int L = 0; L < NLAY; L++) {
            gemm_k<1, 0><<<dim3(TOK / 128, RHID / 64), 256, 0, stream>>>(
                h, rW1 + (size_t)L * DM * RHID, rb1 + L * RHID, nullptr, rh, TOK, RHID, DM);
            router2_k<<<TOK / 256, 256, 0, stream>>>(
                rh, rW2 + (size_t)L * RHID * 3, rb2 + L * 3, mask, counts);
            gemm_k<0, 0><<<dim3(TOK / 128, DM / 64), 256, 0, stream>>>(h, Wq, bq, nullptr, q, TOK, DM, DM);
            gemm_k<0, 0><<<dim3(TOK / 128, DM / 64), 256, 0, stream>>>(h, Wk, bk, nullptr, k, TOK, DM, DM);
            gemm_k<0, 0><<<dim3(TOK / 128, DM / 64), 256, 0, stream>>>(h, Wv, bv, nullptr, v, TOK, DM, DM);
            attn_k<0><<<dim3(SLEN / 64, NHEAD, 2), 256, 0, stream>>>(q, k, v, ab, nullptr, nullptr);
            gemm_k<0, 1><<<dim3(TOK / 128, DM / 64), 256, 0, stream>>>(ab, Wo, bo, h, h1, TOK, DM, DM);
            ln_k<0><<<TOK, 256, 0, stream>>>(h1, ln1g, ln1b, nullptr, nullptr);
            gemm_k<1, 0><<<dim3(TOK / 128, DFFN / 64), 256, 0, stream>>>(h1, Wf1, bf1, nullptr, f1, TOK, DFFN, DM);
            gemm_k<0, 1><<<dim3(TOK / 128, DM / 64), 256, 0, stream>>>(f1, Wf2, bf2, h1, ab, TOK, DM, DFFN);
            ln_k<0><<<TOK, 256, 0, stream>>>(ab, ln2g, ln2b, nullptr, nullptr);
            select_k<0><<<TOK, 256, 0, stream>>>(h, ab, mask, nullptr, nullptr);
        }
        gemm_k<0, 0><<<dim3(TOK / 128, NVOCAB / 64), 256, 0, stream>>>(
            h, Wout, bout, nullptr, out, TOK, NVOCAB, DM);
        scalars_k<<<1, 1, 0, stream>>>(counts, out + (size_t)TOK * NVOCAB);
    }
}